// Round 1
// baseline (1552.379 us; speedup 1.0000x reference)
//
#include <hip/hip_runtime.h>
#include <hip/hip_bf16.h>

#define HID 1000
#define CTX 2000
#define BATCH 64
#define NSEQ 1024
#define M_TOT (BATCH * NSEQ)   // 65536

typedef __attribute__((ext_vector_type(8))) short short8;
typedef __attribute__((ext_vector_type(4))) float floatx4;

// fp32 -> bf16 round-to-nearest-even
__device__ __forceinline__ unsigned short f2bf(float x) {
    union { float f; unsigned u; } v; v.f = x;
    unsigned r = v.u + 0x7FFFu + ((v.u >> 16) & 1u);
    return (unsigned short)(r >> 16);
}

__global__ void zero_kernel(float* __restrict__ out, int n) {
    int i = blockIdx.x * 256 + threadIdx.x;
    if (i < n) out[i] = 0.0f;
}

// W_s[b,h] = sum_d s_prev[b,d] * W_a[h,d]
__global__ void ws_kernel(const float* __restrict__ s_prev,
                          const float* __restrict__ W_a,
                          float* __restrict__ W_s) {
    int h = blockIdx.x * 256 + threadIdx.x;
    int b = blockIdx.y;
    if (h >= HID) return;
    const float* wrow = W_a + (size_t)h * HID;
    const float* srow = s_prev + (size_t)b * HID;
    float acc = 0.0f;
    for (int d = 0; d < HID; d += 4) {
        float4 w = *(const float4*)(wrow + d);
        float4 s = *(const float4*)(srow + d);
        acc += w.x * s.x + w.y * s.y + w.z * s.z + w.w * s.w;
    }
    W_s[b * HID + h] = acc;
}

// Fused: energy = tanh(W_s[b,:] + h_j[b,n,:] @ U_a^T); scores[b,n] += v_a . energy
// GEMM: M = B*N rows of h_j, cols = H (padded 1024), K = CTX (2000, covered by 63*32=2016)
__global__ __launch_bounds__(256) void attn_kernel(
        const float* __restrict__ h_j, const float* __restrict__ U_a,
        const float* __restrict__ W_s, const float* __restrict__ v_a,
        float* __restrict__ out) {
    // LDS tiles, bf16, row stride 40 (=32+8 pad -> 80B rows, <=2-way bank aliasing)
    __shared__ unsigned short As[128 * 40];
    __shared__ unsigned short Bs[128 * 40];

    const int tid  = threadIdx.x;
    const int lane = tid & 63;
    const int wave = tid >> 6;
    const int wm = wave & 1;      // wave row (M dir), 2x2 wave grid
    const int wh = wave >> 1;     // wave col (H dir)
    const int ln   = lane & 15;
    const int quad = lane >> 4;

    const int h0 = blockIdx.x * 128;   // 8 h-tiles (H padded to 1024)
    const int m0 = blockIdx.y * 128;   // 512 m-tiles
    const int b  = m0 >> 10;           // N = 1024, tile never crosses batch rows

    // staging: thread -> (row 0..127, 16-wide segment 0..1)
    const int srow = tid >> 1;
    const int scol = (tid & 1) * 16;

    const float* aptr = h_j + (size_t)(m0 + srow) * CTX;
    const int gh = h0 + srow;
    const bool bvalid = (gh < HID);
    const float* bptr = U_a + (size_t)(bvalid ? gh : 0) * CTX;

    floatx4 acc[4][4];
#pragma unroll
    for (int i = 0; i < 4; i++)
#pragma unroll
        for (int j = 0; j < 4; j++) acc[i][j] = (floatx4)0.0f;

    for (int kk = 0; kk < 63; ++kk) {
        const int c = kk * 32 + scol;
        short8 apk0, apk1, bpk0, bpk1;
        if (c < CTX) {  // c is mult of 16 and CTX%16==0 -> full vector or nothing
            float4 t0 = *(const float4*)(aptr + c);
            float4 t1 = *(const float4*)(aptr + c + 4);
            float4 t2 = *(const float4*)(aptr + c + 8);
            float4 t3 = *(const float4*)(aptr + c + 12);
            apk0[0]=(short)f2bf(t0.x); apk0[1]=(short)f2bf(t0.y); apk0[2]=(short)f2bf(t0.z); apk0[3]=(short)f2bf(t0.w);
            apk0[4]=(short)f2bf(t1.x); apk0[5]=(short)f2bf(t1.y); apk0[6]=(short)f2bf(t1.z); apk0[7]=(short)f2bf(t1.w);
            apk1[0]=(short)f2bf(t2.x); apk1[1]=(short)f2bf(t2.y); apk1[2]=(short)f2bf(t2.z); apk1[3]=(short)f2bf(t2.w);
            apk1[4]=(short)f2bf(t3.x); apk1[5]=(short)f2bf(t3.y); apk1[6]=(short)f2bf(t3.z); apk1[7]=(short)f2bf(t3.w);
        } else {
            apk0 = (short8)0; apk1 = (short8)0;
        }
        if (bvalid && c < CTX) {
            float4 t0 = *(const float4*)(bptr + c);
            float4 t1 = *(const float4*)(bptr + c + 4);
            float4 t2 = *(const float4*)(bptr + c + 8);
            float4 t3 = *(const float4*)(bptr + c + 12);
            bpk0[0]=(short)f2bf(t0.x); bpk0[1]=(short)f2bf(t0.y); bpk0[2]=(short)f2bf(t0.z); bpk0[3]=(short)f2bf(t0.w);
            bpk0[4]=(short)f2bf(t1.x); bpk0[5]=(short)f2bf(t1.y); bpk0[6]=(short)f2bf(t1.z); bpk0[7]=(short)f2bf(t1.w);
            bpk1[0]=(short)f2bf(t2.x); bpk1[1]=(short)f2bf(t2.y); bpk1[2]=(short)f2bf(t2.z); bpk1[3]=(short)f2bf(t2.w);
            bpk1[4]=(short)f2bf(t3.x); bpk1[5]=(short)f2bf(t3.y); bpk1[6]=(short)f2bf(t3.z); bpk1[7]=(short)f2bf(t3.w);
        } else {
            bpk0 = (short8)0; bpk1 = (short8)0;
        }

        __syncthreads();  // previous iter's reads done
        *(short8*)&As[srow * 40 + scol]     = apk0;
        *(short8*)&As[srow * 40 + scol + 8] = apk1;
        *(short8*)&Bs[srow * 40 + scol]     = bpk0;
        *(short8*)&Bs[srow * 40 + scol + 8] = bpk1;
        __syncthreads();  // tile visible

        short8 af[4], bf[4];
#pragma unroll
        for (int i = 0; i < 4; i++)
            af[i] = *(const short8*)&As[(wm * 64 + i * 16 + ln) * 40 + quad * 8];
#pragma unroll
        for (int j = 0; j < 4; j++)
            bf[j] = *(const short8*)&Bs[(wh * 64 + j * 16 + ln) * 40 + quad * 8];
#pragma unroll
        for (int i = 0; i < 4; i++)
#pragma unroll
            for (int j = 0; j < 4; j++)
                acc[i][j] = __builtin_amdgcn_mfma_f32_16x16x32_bf16(af[i], bf[j], acc[i][j], 0, 0, 0);
    }

    // Epilogue: e = tanh(acc + W_s[b,h]); rowsum += v_a[h]*e; reduce over 16 cols
    float rowsum[4][4];
#pragma unroll
    for (int i = 0; i < 4; i++)
#pragma unroll
        for (int r = 0; r < 4; r++) rowsum[i][r] = 0.0f;

#pragma unroll
    for (int j = 0; j < 4; j++) {
        const int h = h0 + wh * 64 + j * 16 + ln;
        float wsv = 0.0f, vav = 0.0f;
        if (h < HID) { wsv = W_s[b * HID + h]; vav = v_a[h]; }
#pragma unroll
        for (int i = 0; i < 4; i++)
#pragma unroll
            for (int r = 0; r < 4; r++)
                rowsum[i][r] += vav * tanhf(acc[i][j][r] + wsv);
    }

#pragma unroll
    for (int i = 0; i < 4; i++)
#pragma unroll
        for (int r = 0; r < 4; r++) {
            float v = rowsum[i][r];
            v += __shfl_xor(v, 1);
            v += __shfl_xor(v, 2);
            v += __shfl_xor(v, 4);
            v += __shfl_xor(v, 8);
            rowsum[i][r] = v;
        }

    if (ln == 0) {
#pragma unroll
        for (int i = 0; i < 4; i++) {
            const int row = m0 + wm * 64 + i * 16 + quad * 4;
#pragma unroll
            for (int r = 0; r < 4; r++)
                atomicAdd(&out[row + r], rowsum[i][r]);
        }
    }
}

extern "C" void kernel_launch(void* const* d_in, const int* in_sizes, int n_in,
                              void* d_out, int out_size, void* d_ws, size_t ws_size,
                              hipStream_t stream) {
    const float* s_prev = (const float*)d_in[0];
    const float* h_j    = (const float*)d_in[1];
    const float* W_a    = (const float*)d_in[2];
    const float* U_a    = (const float*)d_in[3];
    const float* v_a    = (const float*)d_in[4];
    float* out = (float*)d_out;
    float* W_s = (float*)d_ws;  // 64*1000 floats = 256 KB scratch

    zero_kernel<<<dim3(M_TOT / 256), 256, 0, stream>>>(out, M_TOT);
    ws_kernel<<<dim3(4, 64), 256, 0, stream>>>(s_prev, W_a, W_s);
    attn_kernel<<<dim3(8, 512), 256, 0, stream>>>(h_j, U_a, W_s, v_a, out);
}

// Round 2
// 1222.223 us; speedup vs baseline: 1.2701x; 1.2701x over previous
//
#include <hip/hip_runtime.h>
#include <hip/hip_bf16.h>

#define HID 1000
#define CTX 2000
#define KP   2016          // K padded to 63*32
#define HP   1024          // H padded to 8*128
#define BATCH 64
#define NSEQ 1024
#define M_TOT (BATCH * NSEQ)   // 65536
#define WSTR 1024              // W_s row stride

typedef __attribute__((ext_vector_type(8))) short short8;
typedef __attribute__((ext_vector_type(4))) float floatx4;

// fp32 -> bf16 round-to-nearest-even
__device__ __forceinline__ unsigned short f2bf(float x) {
    union { float f; unsigned u; } v; v.f = x;
    unsigned r = v.u + 0x7FFFu + ((v.u >> 16) & 1u);
    return (unsigned short)(r >> 16);
}

// async global->LDS, 16B per lane; LDS dest = wave-uniform base + lane*16
typedef const __attribute__((address_space(1))) unsigned glb_u32;
typedef __attribute__((address_space(3))) unsigned lds_u32;
__device__ __forceinline__ void gload16(const void* g, void* l) {
    __builtin_amdgcn_global_load_lds((glb_u32*)g, (lds_u32*)l, 16, 0, 0);
}

__global__ void zero_kernel(float* __restrict__ out, int n) {
    int i = blockIdx.x * 256 + threadIdx.x;
    if (i < n) out[i] = 0.0f;
}

// h_j (M_TOT x CTX fp32) -> A_bf (M_TOT x KP bf16), zero-pad cols >= CTX
__global__ void convertA_kernel(const float* __restrict__ src, unsigned short* __restrict__ dst) {
    int row = blockIdx.x;
    int t = threadIdx.x;           // 8-col group
    if (t >= KP / 8) return;       // 252 groups
    unsigned short pk[8];
    if (t < CTX / 8) {
        const float* p = src + (size_t)row * CTX + t * 8;
        float4 a = *(const float4*)p;
        float4 b = *(const float4*)(p + 4);
        pk[0]=f2bf(a.x); pk[1]=f2bf(a.y); pk[2]=f2bf(a.z); pk[3]=f2bf(a.w);
        pk[4]=f2bf(b.x); pk[5]=f2bf(b.y); pk[6]=f2bf(b.z); pk[7]=f2bf(b.w);
    } else {
#pragma unroll
        for (int i = 0; i < 8; i++) pk[i] = 0;
    }
    *(short8*)(dst + (size_t)row * KP + t * 8) = *(short8*)pk;
}

// U_a (HID x CTX fp32) -> B_bf (HP x KP bf16), zero-pad rows >= HID, cols >= CTX
__global__ void convertB_kernel(const float* __restrict__ src, unsigned short* __restrict__ dst) {
    int row = blockIdx.x;          // 0..HP-1
    int t = threadIdx.x;
    if (t >= KP / 8) return;
    unsigned short pk[8];
    if (row < HID && t < CTX / 8) {
        const float* p = src + (size_t)row * CTX + t * 8;
        float4 a = *(const float4*)p;
        float4 b = *(const float4*)(p + 4);
        pk[0]=f2bf(a.x); pk[1]=f2bf(a.y); pk[2]=f2bf(a.z); pk[3]=f2bf(a.w);
        pk[4]=f2bf(b.x); pk[5]=f2bf(b.y); pk[6]=f2bf(b.z); pk[7]=f2bf(b.w);
    } else {
#pragma unroll
        for (int i = 0; i < 8; i++) pk[i] = 0;
    }
    *(short8*)(dst + (size_t)row * KP + t * 8) = *(short8*)pk;
}

// W_s[b,h] = sum_d s_prev[b,d] * W_a[h,d] — one wave per (b,h), coalesced row reads
__global__ void ws_kernel(const float* __restrict__ s_prev,
                          const float* __restrict__ W_a,
                          float* __restrict__ W_s) {
    int wave = threadIdx.x >> 6, lane = threadIdx.x & 63;
    int gw = blockIdx.x * 4 + wave;      // 0 .. 63999
    int b = gw / HID, h = gw % HID;
    const float* wr = W_a + (size_t)h * HID;
    const float* sr = s_prev + (size_t)b * HID;
    float acc = 0.0f;
#pragma unroll
    for (int it = 0; it < 4; ++it) {
        int idx = it * 64 + lane;        // float4 index, HID/4 = 250
        if (idx < HID / 4) {
            float4 w = *(const float4*)(wr + idx * 4);
            float4 s = *(const float4*)(sr + idx * 4);
            acc += w.x * s.x + w.y * s.y + w.z * s.z + w.w * s.w;
        }
    }
    acc += __shfl_xor(acc, 1);
    acc += __shfl_xor(acc, 2);
    acc += __shfl_xor(acc, 4);
    acc += __shfl_xor(acc, 8);
    acc += __shfl_xor(acc, 16);
    acc += __shfl_xor(acc, 32);
    if (lane == 0) W_s[b * WSTR + h] = acc;
}

// m97-style GEMM: C[m][h] = sum_k A_bf[m][k] * B_bf[h][k], fused tanh+v_a epilogue.
// 128x128 tile, BK=32, global_load_lds(16B), LDS stride 32 (no pad), 2 barriers/iter.
__global__ __launch_bounds__(256) void gemm_kernel(
        const unsigned short* __restrict__ A, const unsigned short* __restrict__ B,
        const float* __restrict__ W_s, const float* __restrict__ v_a,
        float* __restrict__ out) {
    __shared__ __align__(16) unsigned short As[128 * 32];
    __shared__ __align__(16) unsigned short Bs[128 * 32];

    const int tid  = threadIdx.x;
    const int lane = tid & 63;
    const int wave = tid >> 6;
    const int wm = wave & 1, wh = wave >> 1;
    const int ln = lane & 15, quad = lane >> 4;

    const int h0 = blockIdx.x * 128;   // 8 h-tiles
    const int m0 = blockIdx.y * 128;   // 512 m-tiles
    const int b  = m0 >> 10;           // NSEQ=1024: tile never crosses batch rows

    // staging: wave w, instr q stages rows [q*64 + w*16, +16), lane -> (row>>2, chunk&3)
    const int srow = lane >> 2;            // 0..15
    const int scol = (lane & 3) * 8;       // element offset of this lane's 16B chunk
    const unsigned short* aptr0 = A + (size_t)(m0 + wave * 16 + srow) * KP + scol;
    const unsigned short* aptr1 = aptr0 + (size_t)64 * KP;
    const unsigned short* bptr0 = B + (size_t)(h0 + wave * 16 + srow) * KP + scol;
    const unsigned short* bptr1 = bptr0 + (size_t)64 * KP;
    unsigned short* asl0 = &As[(wave * 16) * 32];
    unsigned short* asl1 = &As[(64 + wave * 16) * 32];
    unsigned short* bsl0 = &Bs[(wave * 16) * 32];
    unsigned short* bsl1 = &Bs[(64 + wave * 16) * 32];

    floatx4 acc[4][4];
#pragma unroll
    for (int i = 0; i < 4; i++)
#pragma unroll
        for (int j = 0; j < 4; j++) acc[i][j] = (floatx4)0.0f;

    for (int kk = 0; kk < KP / 32; ++kk) {   // 63 iters, no edge cases
        __syncthreads();                     // prev iter's LDS reads done
        gload16(aptr0, asl0);
        gload16(aptr1, asl1);
        gload16(bptr0, bsl0);
        gload16(bptr1, bsl1);
        aptr0 += 32; aptr1 += 32; bptr0 += 32; bptr1 += 32;
        __syncthreads();                     // vmcnt(0) drained at barrier -> tile visible

        short8 af[4], bfr[4];
#pragma unroll
        for (int i = 0; i < 4; i++)
            af[i] = *(const short8*)&As[(wm * 64 + i * 16 + ln) * 32 + quad * 8];
#pragma unroll
        for (int j = 0; j < 4; j++)
            bfr[j] = *(const short8*)&Bs[(wh * 64 + j * 16 + ln) * 32 + quad * 8];
#pragma unroll
        for (int i = 0; i < 4; i++)
#pragma unroll
            for (int j = 0; j < 4; j++)
                acc[i][j] = __builtin_amdgcn_mfma_f32_16x16x32_bf16(af[i], bfr[j], acc[i][j], 0, 0, 0);
    }

    // Epilogue: e = tanh(acc + W_s[b,h]); rowsum += v_a[h]*e; reduce over 16 cols (n=ln)
    float rowsum[4][4];
#pragma unroll
    for (int i = 0; i < 4; i++)
#pragma unroll
        for (int r = 0; r < 4; r++) rowsum[i][r] = 0.0f;

#pragma unroll
    for (int j = 0; j < 4; j++) {
        const int h = h0 + wh * 64 + j * 16 + ln;
        float wsv = 0.0f, vav = 0.0f;
        if (h < HID) { wsv = W_s[b * WSTR + h]; vav = v_a[h]; }
#pragma unroll
        for (int i = 0; i < 4; i++)
#pragma unroll
            for (int r = 0; r < 4; r++)
                rowsum[i][r] += vav * tanhf(acc[i][j][r] + wsv);
    }

#pragma unroll
    for (int i = 0; i < 4; i++)
#pragma unroll
        for (int r = 0; r < 4; r++) {
            float v = rowsum[i][r];
            v += __shfl_xor(v, 1);
            v += __shfl_xor(v, 2);
            v += __shfl_xor(v, 4);
            v += __shfl_xor(v, 8);
            rowsum[i][r] = v;
        }

    if (ln == 0) {
#pragma unroll
        for (int i = 0; i < 4; i++) {
            const int row = m0 + wm * 64 + i * 16 + quad * 4;
#pragma unroll
            for (int r = 0; r < 4; r++)
                atomicAdd(&out[row + r], rowsum[i][r]);
        }
    }
}

// ---------------- fallback (round-1 fused path, if ws too small) ----------------
__global__ __launch_bounds__(256) void attn_fallback(
        const float* __restrict__ h_j, const float* __restrict__ U_a,
        const float* __restrict__ W_s, const float* __restrict__ v_a,
        float* __restrict__ out) {
    __shared__ unsigned short As[128 * 40];
    __shared__ unsigned short Bs[128 * 40];
    const int tid = threadIdx.x, lane = tid & 63, wave = tid >> 6;
    const int wm = wave & 1, wh = wave >> 1, ln = lane & 15, quad = lane >> 4;
    const int h0 = blockIdx.x * 128, m0 = blockIdx.y * 128, b = m0 >> 10;
    const int srow = tid >> 1, scol = (tid & 1) * 16;
    const float* aptr = h_j + (size_t)(m0 + srow) * CTX;
    const int gh = h0 + srow;
    const bool bvalid = (gh < HID);
    const float* bptr = U_a + (size_t)(bvalid ? gh : 0) * CTX;
    floatx4 acc[4][4];
#pragma unroll
    for (int i = 0; i < 4; i++)
#pragma unroll
        for (int j = 0; j < 4; j++) acc[i][j] = (floatx4)0.0f;
    for (int kk = 0; kk < 63; ++kk) {
        const int c = kk * 32 + scol;
        short8 apk0 = (short8)0, apk1 = (short8)0, bpk0 = (short8)0, bpk1 = (short8)0;
        if (c < CTX) {
            float4 t0 = *(const float4*)(aptr + c), t1 = *(const float4*)(aptr + c + 4);
            float4 t2 = *(const float4*)(aptr + c + 8), t3 = *(const float4*)(aptr + c + 12);
            apk0[0]=(short)f2bf(t0.x); apk0[1]=(short)f2bf(t0.y); apk0[2]=(short)f2bf(t0.z); apk0[3]=(short)f2bf(t0.w);
            apk0[4]=(short)f2bf(t1.x); apk0[5]=(short)f2bf(t1.y); apk0[6]=(short)f2bf(t1.z); apk0[7]=(short)f2bf(t1.w);
            apk1[0]=(short)f2bf(t2.x); apk1[1]=(short)f2bf(t2.y); apk1[2]=(short)f2bf(t2.z); apk1[3]=(short)f2bf(t2.w);
            apk1[4]=(short)f2bf(t3.x); apk1[5]=(short)f2bf(t3.y); apk1[6]=(short)f2bf(t3.z); apk1[7]=(short)f2bf(t3.w);
        }
        if (bvalid && c < CTX) {
            float4 t0 = *(const float4*)(bptr + c), t1 = *(const float4*)(bptr + c + 4);
            float4 t2 = *(const float4*)(bptr + c + 8), t3 = *(const float4*)(bptr + c + 12);
            bpk0[0]=(short)f2bf(t0.x); bpk0[1]=(short)f2bf(t0.y); bpk0[2]=(short)f2bf(t0.z); bpk0[3]=(short)f2bf(t0.w);
            bpk0[4]=(short)f2bf(t1.x); bpk0[5]=(short)f2bf(t1.y); bpk0[6]=(short)f2bf(t1.z); bpk0[7]=(short)f2bf(t1.w);
            bpk1[0]=(short)f2bf(t2.x); bpk1[1]=(short)f2bf(t2.y); bpk1[2]=(short)f2bf(t2.z); bpk1[3]=(short)f2bf(t2.w);
            bpk1[4]=(short)f2bf(t3.x); bpk1[5]=(short)f2bf(t3.y); bpk1[6]=(short)f2bf(t3.z); bpk1[7]=(short)f2bf(t3.w);
        }
        __syncthreads();
        *(short8*)&As[srow * 40 + scol]     = apk0;
        *(short8*)&As[srow * 40 + scol + 8] = apk1;
        *(short8*)&Bs[srow * 40 + scol]     = bpk0;
        *(short8*)&Bs[srow * 40 + scol + 8] = bpk1;
        __syncthreads();
        short8 af[4], bfr[4];
#pragma unroll
        for (int i = 0; i < 4; i++) af[i] = *(const short8*)&As[(wm * 64 + i * 16 + ln) * 40 + quad * 8];
#pragma unroll
        for (int j = 0; j < 4; j++) bfr[j] = *(const short8*)&Bs[(wh * 64 + j * 16 + ln) * 40 + quad * 8];
#pragma unroll
        for (int i = 0; i < 4; i++)
#pragma unroll
            for (int j = 0; j < 4; j++)
                acc[i][j] = __builtin_amdgcn_mfma_f32_16x16x32_bf16(af[i], bfr[j], acc[i][j], 0, 0, 0);
    }
    float rowsum[4][4];
#pragma unroll
    for (int i = 0; i < 4; i++)
#pragma unroll
        for (int r = 0; r < 4; r++) rowsum[i][r] = 0.0f;
#pragma unroll
    for (int j = 0; j < 4; j++) {
        const int h = h0 + wh * 64 + j * 16 + ln;
        float wsv = 0.0f, vav = 0.0f;
        if (h < HID) { wsv = W_s[b * WSTR + h]; vav = v_a[h]; }
#pragma unroll
        for (int i = 0; i < 4; i++)
#pragma unroll
            for (int r = 0; r < 4; r++)
                rowsum[i][r] += vav * tanhf(acc[i][j][r] + wsv);
    }
#pragma unroll
    for (int i = 0; i < 4; i++)
#pragma unroll
        for (int r = 0; r < 4; r++) {
            float v = rowsum[i][r];
            v += __shfl_xor(v, 1); v += __shfl_xor(v, 2);
            v += __shfl_xor(v, 4); v += __shfl_xor(v, 8);
            rowsum[i][r] = v;
        }
    if (ln == 0) {
#pragma unroll
        for (int i = 0; i < 4; i++) {
            const int row = m0 + wm * 64 + i * 16 + quad * 4;
#pragma unroll
            for (int r = 0; r < 4; r++) atomicAdd(&out[row + r], rowsum[i][r]);
        }
    }
}

extern "C" void kernel_launch(void* const* d_in, const int* in_sizes, int n_in,
                              void* d_out, int out_size, void* d_ws, size_t ws_size,
                              hipStream_t stream) {
    const float* s_prev = (const float*)d_in[0];
    const float* h_j    = (const float*)d_in[1];
    const float* W_a    = (const float*)d_in[2];
    const float* U_a    = (const float*)d_in[3];
    const float* v_a    = (const float*)d_in[4];
    float* out = (float*)d_out;

    // ws layout: [W_s 64*1024 f32][B_bf HP*KP bf16][A_bf M_TOT*KP bf16]
    const size_t ws_off   = 0;
    const size_t b_off    = 64 * WSTR * sizeof(float);                 // 262144
    const size_t a_off    = b_off + (size_t)HP * KP * sizeof(short);   // +4128768
    const size_t need     = a_off + (size_t)M_TOT * KP * sizeof(short);

    float* W_s = (float*)((char*)d_ws + ws_off);

    zero_kernel<<<dim3(M_TOT / 256), 256, 0, stream>>>(out, M_TOT);
    ws_kernel<<<dim3(BATCH * HID / 4), 256, 0, stream>>>(s_prev, W_a, W_s);

    if (ws_size >= need) {
        unsigned short* B_bf = (unsigned short*)((char*)d_ws + b_off);
        unsigned short* A_bf = (unsigned short*)((char*)d_ws + a_off);
        convertA_kernel<<<dim3(M_TOT), 256, 0, stream>>>(h_j, A_bf);
        convertB_kernel<<<dim3(HP), 256, 0, stream>>>(U_a, B_bf);
        gemm_kernel<<<dim3(HP / 128, M_TOT / 128), 256, 0, stream>>>(A_bf, B_bf, W_s, v_a, out);
    } else {
        attn_fallback<<<dim3(HP / 128, M_TOT / 128), 256, 0, stream>>>(h_j, U_a, W_s, v_a, out);
    }
}

// Round 3
// 1189.877 us; speedup vs baseline: 1.3047x; 1.0272x over previous
//
#include <hip/hip_runtime.h>
#include <hip/hip_bf16.h>

#define HID 1000
#define CTX 2000
#define KP   2016          // K padded to 63*32
#define HP   1024          // H padded to 8*128
#define BATCH 64
#define NSEQ 1024
#define M_TOT (BATCH * NSEQ)   // 65536
#define WSTR 1024              // W_s row stride

typedef __attribute__((ext_vector_type(8))) short short8;
typedef __attribute__((ext_vector_type(4))) float floatx4;

// fp32 -> bf16 round-to-nearest-even
__device__ __forceinline__ unsigned short f2bf(float x) {
    union { float f; unsigned u; } v; v.f = x;
    unsigned r = v.u + 0x7FFFu + ((v.u >> 16) & 1u);
    return (unsigned short)(r >> 16);
}

// async global->LDS, 16B per lane; LDS dest = wave-uniform base + lane*16
typedef const __attribute__((address_space(1))) unsigned glb_u32;
typedef __attribute__((address_space(3))) unsigned lds_u32;
__device__ __forceinline__ void gload16(const void* g, void* l) {
    __builtin_amdgcn_global_load_lds((glb_u32*)g, (lds_u32*)l, 16, 0, 0);
}

__global__ void zero_kernel(float* __restrict__ out, int n) {
    int i = blockIdx.x * 256 + threadIdx.x;
    if (i < n) out[i] = 0.0f;
}

// h_j (M_TOT x CTX fp32) -> A_bf (M_TOT x KP bf16), zero-pad cols >= CTX
__global__ void convertA_kernel(const float* __restrict__ src, unsigned short* __restrict__ dst) {
    int row = blockIdx.x;
    int t = threadIdx.x;           // 8-col group
    if (t >= KP / 8) return;       // 252 groups
    unsigned short pk[8];
    if (t < CTX / 8) {
        const float* p = src + (size_t)row * CTX + t * 8;
        float4 a = *(const float4*)p;
        float4 b = *(const float4*)(p + 4);
        pk[0]=f2bf(a.x); pk[1]=f2bf(a.y); pk[2]=f2bf(a.z); pk[3]=f2bf(a.w);
        pk[4]=f2bf(b.x); pk[5]=f2bf(b.y); pk[6]=f2bf(b.z); pk[7]=f2bf(b.w);
    } else {
#pragma unroll
        for (int i = 0; i < 8; i++) pk[i] = 0;
    }
    *(short8*)(dst + (size_t)row * KP + t * 8) = *(short8*)pk;
}

// U_a (HID x CTX fp32) -> B_bf (HP x KP bf16), zero-pad rows >= HID, cols >= CTX
__global__ void convertB_kernel(const float* __restrict__ src, unsigned short* __restrict__ dst) {
    int row = blockIdx.x;          // 0..HP-1
    int t = threadIdx.x;
    if (t >= KP / 8) return;
    unsigned short pk[8];
    if (row < HID && t < CTX / 8) {
        const float* p = src + (size_t)row * CTX + t * 8;
        float4 a = *(const float4*)p;
        float4 b = *(const float4*)(p + 4);
        pk[0]=f2bf(a.x); pk[1]=f2bf(a.y); pk[2]=f2bf(a.z); pk[3]=f2bf(a.w);
        pk[4]=f2bf(b.x); pk[5]=f2bf(b.y); pk[6]=f2bf(b.z); pk[7]=f2bf(b.w);
    } else {
#pragma unroll
        for (int i = 0; i < 8; i++) pk[i] = 0;
    }
    *(short8*)(dst + (size_t)row * KP + t * 8) = *(short8*)pk;
}

// W_s[b,h] = sum_d s_prev[b,d] * W_a[h,d] — one wave per (b,h), coalesced row reads
__global__ void ws_kernel(const float* __restrict__ s_prev,
                          const float* __restrict__ W_a,
                          float* __restrict__ W_s) {
    int wave = threadIdx.x >> 6, lane = threadIdx.x & 63;
    int gw = blockIdx.x * 4 + wave;      // 0 .. 63999
    int b = gw / HID, h = gw % HID;
    const float* wr = W_a + (size_t)h * HID;
    const float* sr = s_prev + (size_t)b * HID;
    float acc = 0.0f;
#pragma unroll
    for (int it = 0; it < 4; ++it) {
        int idx = it * 64 + lane;        // float4 index, HID/4 = 250
        if (idx < HID / 4) {
            float4 w = *(const float4*)(wr + idx * 4);
            float4 s = *(const float4*)(sr + idx * 4);
            acc += w.x * s.x + w.y * s.y + w.z * s.z + w.w * s.w;
        }
    }
    acc += __shfl_xor(acc, 1);
    acc += __shfl_xor(acc, 2);
    acc += __shfl_xor(acc, 4);
    acc += __shfl_xor(acc, 8);
    acc += __shfl_xor(acc, 16);
    acc += __shfl_xor(acc, 32);
    if (lane == 0) W_s[b * WSTR + h] = acc;
}

// GEMM, one block per 128-row m-tile; inner loop over all 8 h-tiles so the
// A m-tile (516 KB) stays hot in THIS XCD's L2 after the first h pass.
// 2x2 wave grid, BK=32, global_load_lds(16B), 2 barriers/iter (m97 structure).
// rowsum accumulates across h-tiles in registers; one atomic pass at the end.
__global__ __launch_bounds__(256, 2) void gemm_kernel(
        const unsigned short* __restrict__ A, const unsigned short* __restrict__ B,
        const float* __restrict__ W_s, const float* __restrict__ v_a,
        float* __restrict__ out) {
    __shared__ __align__(16) unsigned short As[128 * 32];
    __shared__ __align__(16) unsigned short Bs[128 * 32];

    const int tid  = threadIdx.x;
    const int lane = tid & 63;
    const int wave = tid >> 6;
    const int wm = wave & 1, wh = wave >> 1;
    const int ln = lane & 15, quad = lane >> 4;

    const int m0 = blockIdx.x * 128;   // 512 m-tiles
    const int b  = m0 >> 10;           // NSEQ=1024: tile never crosses batch rows

    // staging: wave w, instr q stages rows [q*64 + w*16, +16), lane -> (row>>2, chunk&3)
    const int srow = lane >> 2;            // 0..15
    const int scol = (lane & 3) * 8;       // element offset of lane's 16B chunk
    const unsigned short* abase0 = A + (size_t)(m0 + wave * 16 + srow) * KP + scol;
    const unsigned short* abase1 = abase0 + (size_t)64 * KP;
    unsigned short* asl0 = &As[(wave * 16) * 32];
    unsigned short* asl1 = &As[(64 + wave * 16) * 32];
    unsigned short* bsl0 = &Bs[(wave * 16) * 32];
    unsigned short* bsl1 = &Bs[(64 + wave * 16) * 32];

    float rowsum[4][4];
#pragma unroll
    for (int i = 0; i < 4; i++)
#pragma unroll
        for (int r = 0; r < 4; r++) rowsum[i][r] = 0.0f;

    for (int ht = 0; ht < HP / 128; ++ht) {   // 8 h-tiles
        const unsigned short* aptr0 = abase0;
        const unsigned short* aptr1 = abase1;
        const unsigned short* bptr0 = B + (size_t)(ht * 128 + wave * 16 + srow) * KP + scol;
        const unsigned short* bptr1 = bptr0 + (size_t)64 * KP;

        floatx4 acc[4][4];
#pragma unroll
        for (int i = 0; i < 4; i++)
#pragma unroll
            for (int j = 0; j < 4; j++) acc[i][j] = (floatx4)0.0f;

        for (int kk = 0; kk < KP / 32; ++kk) {   // 63 iters, no edge cases
            __syncthreads();                     // prev iter's LDS reads done
            gload16(aptr0, asl0);
            gload16(aptr1, asl1);
            gload16(bptr0, bsl0);
            gload16(bptr1, bsl1);
            aptr0 += 32; aptr1 += 32; bptr0 += 32; bptr1 += 32;
            __syncthreads();                     // vmcnt(0) drained -> tile visible

            short8 af[4], bfr[4];
#pragma unroll
            for (int i = 0; i < 4; i++)
                af[i] = *(const short8*)&As[(wm * 64 + i * 16 + ln) * 32 + quad * 8];
#pragma unroll
            for (int j = 0; j < 4; j++)
                bfr[j] = *(const short8*)&Bs[(wh * 64 + j * 16 + ln) * 32 + quad * 8];
#pragma unroll
            for (int i = 0; i < 4; i++)
#pragma unroll
                for (int j = 0; j < 4; j++)
                    acc[i][j] = __builtin_amdgcn_mfma_f32_16x16x32_bf16(af[i], bfr[j], acc[i][j], 0, 0, 0);
        }

        // partial epilogue for this h-tile: rowsum += v_a[h] * tanh(acc + W_s[b,h])
#pragma unroll
        for (int j = 0; j < 4; j++) {
            const int h = ht * 128 + wh * 64 + j * 16 + ln;
            float wsv = 0.0f, vav = 0.0f;
            if (h < HID) { wsv = W_s[b * WSTR + h]; vav = v_a[h]; }
#pragma unroll
            for (int i = 0; i < 4; i++)
#pragma unroll
                for (int r = 0; r < 4; r++)
                    rowsum[i][r] += vav * tanhf(acc[i][j][r] + wsv);
        }
    }

    // reduce over 16 h-lanes; 2 waves (wh=0/1) share rows -> atomicAdd into zeroed out
#pragma unroll
    for (int i = 0; i < 4; i++)
#pragma unroll
        for (int r = 0; r < 4; r++) {
            float v = rowsum[i][r];
            v += __shfl_xor(v, 1);
            v += __shfl_xor(v, 2);
            v += __shfl_xor(v, 4);
            v += __shfl_xor(v, 8);
            rowsum[i][r] = v;
        }

    if (ln == 0) {
#pragma unroll
        for (int i = 0; i < 4; i++) {
            const int row = m0 + wm * 64 + i * 16 + quad * 4;
#pragma unroll
            for (int r = 0; r < 4; r++)
                atomicAdd(&out[row + r], rowsum[i][r]);
        }
    }
}

extern "C" void kernel_launch(void* const* d_in, const int* in_sizes, int n_in,
                              void* d_out, int out_size, void* d_ws, size_t ws_size,
                              hipStream_t stream) {
    const float* s_prev = (const float*)d_in[0];
    const float* h_j    = (const float*)d_in[1];
    const float* W_a    = (const float*)d_in[2];
    const float* U_a    = (const float*)d_in[3];
    const float* v_a    = (const float*)d_in[4];
    float* out = (float*)d_out;

    // ws layout: [W_s 64*1024 f32][B_bf HP*KP bf16][A_bf M_TOT*KP bf16]
    const size_t b_off = 64 * WSTR * sizeof(float);                 // 262144
    const size_t a_off = b_off + (size_t)HP * KP * sizeof(short);   // +4128768
    float* W_s = (float*)d_ws;
    unsigned short* B_bf = (unsigned short*)((char*)d_ws + b_off);
    unsigned short* A_bf = (unsigned short*)((char*)d_ws + a_off);

    zero_kernel<<<dim3(M_TOT / 256), 256, 0, stream>>>(out, M_TOT);
    ws_kernel<<<dim3(BATCH * HID / 4), 256, 0, stream>>>(s_prev, W_a, W_s);
    convertA_kernel<<<dim3(M_TOT), 256, 0, stream>>>(h_j, A_bf);
    convertB_kernel<<<dim3(HP), 256, 0, stream>>>(U_a, B_bf);
    gemm_kernel<<<dim3(M_TOT / 128), 256, 0, stream>>>(A_bf, B_bf, W_s, v_a, out);
}